// Round 6
// baseline (73.722 us; speedup 1.0000x reference)
//
#include <hip/hip_runtime.h>
#include <math.h>

// Problem constants: B=32, L=2048, F=512, K=128, LOUT=1921
#define BB 32
#define LL 2048
#define FF 512
#define KK 128
#define LOUT (LL - KK + 1)      // 1921
#define TCHUNK 8
#define NC ((LOUT + TCHUNK - 1) / TCHUNK)   // 241 chunks
#define NPAIR ((NC + 1) / 2)                // 121 chunk-pairs per batch
#define F4 (FF / 4)             // 128

typedef float vfloat4 __attribute__((ext_vector_type(4)));

// ---------------------------------------------------------------------------
// Kernel 1: tau[b,f] = sigmoid((x[b,L-1,:] . W[f,:] + bias[f]) / 10 - 3)
//           norm[b,f] = 1 / sum_{i=0..K-1} tau^i   (Horner)
//           tauK[b,f] = tau^K                       (7 squarings)
// ---------------------------------------------------------------------------
__global__ __launch_bounds__(128) void tau_kernel(const float* __restrict__ x,
                                                  const float* __restrict__ W,
                                                  const float* __restrict__ bias,
                                                  float* __restrict__ tau_out,
                                                  float* __restrict__ norm_out,
                                                  float* __restrict__ tauK_out) {
    __shared__ float feat[FF];
    const int b   = blockIdx.x >> 2;
    const int fq  = blockIdx.x & 3;
    const int tid = threadIdx.x;

    ((float4*)feat)[tid] =
        ((const float4*)(x + ((size_t)b * LL + (LL - 1)) * FF))[tid];
    __syncthreads();

    const int f = fq * 128 + tid;
    const float4* __restrict__ Wrow = (const float4*)(W + (size_t)f * FF);
    const float4* __restrict__ fv   = (const float4*)feat;

    float a0 = 0.f, a1 = 0.f, a2 = 0.f, a3 = 0.f;
#pragma unroll 4
    for (int j = 0; j < F4; j += 2) {
        float4 w0 = Wrow[j],     w1 = Wrow[j + 1];
        float4 x0 = fv[j],       x1 = fv[j + 1];
        a0 = fmaf(w0.x, x0.x, a0); a1 = fmaf(w0.y, x0.y, a1);
        a2 = fmaf(w0.z, x0.z, a2); a3 = fmaf(w0.w, x0.w, a3);
        a0 = fmaf(w1.x, x1.x, a0); a1 = fmaf(w1.y, x1.y, a1);
        a2 = fmaf(w1.z, x1.z, a2); a3 = fmaf(w1.w, x1.w, a3);
    }
    const float acc = (a0 + a1) + (a2 + a3);
    const float z   = (acc + bias[f]) * 0.1f - 3.0f;
    const float tau = 1.0f / (1.0f + expf(-z));

    float den = 1.0f;
#pragma unroll 8
    for (int i = 0; i < KK - 1; ++i) den = fmaf(den, tau, 1.0f);

    float tk = tau;
#pragma unroll
    for (int i = 0; i < 7; ++i) tk *= tk;

    const int idx = b * FF + f;
    tau_out[idx]  = tau;
    norm_out[idx] = 1.0f / den;
    tauK_out[idx] = tk;
}

__device__ __forceinline__ void nt_store4(float4* p, float a, float b, float c,
                                          float d) {
    vfloat4 v = {a, b, c, d};
    __builtin_nontemporal_store(v, (vfloat4*)p);
}

// ---------------------------------------------------------------------------
// Kernel 2: TLP-max version. Grid = B * NPAIR blocks of 256 threads.
// Thread (sub, f4): sub = tid>>7 picks chunk 2p+sub (8 output rows), f4 =
// tid&127 picks the float4 feature column. ~15.5K waves -> 32 waves/CU
// resident; latency hidden by TLP, not compiler-fought ILP.
//   warm-up: Horner over last T taps of first window (T from tau decay,
//            clamped to K for tau->1 => exact for any data)
//   steady : S = tau*S + x[t+K-1]; out[t] = norm*S  (7 iters, full unroll)
// Stores nontemporal (write-once; keeps x resident in L3).
// ---------------------------------------------------------------------------
__global__ __launch_bounds__(256) void fir_kernel(const float* __restrict__ x,
                                                  const float* __restrict__ tau_arr,
                                                  const float* __restrict__ norm_arr,
                                                  const float* __restrict__ tauK_arr,
                                                  float* __restrict__ out) {
    const int b   = blockIdx.x / NPAIR;
    const int p   = blockIdx.x % NPAIR;
    const int sub = threadIdx.x >> 7;
    const int f4  = threadIdx.x & 127;
    const int c   = 2 * p + sub;
    const int t0  = c * TCHUNK;
    if (t0 >= LOUT) return;
    const int nout = ((t0 + TCHUNK <= LOUT) ? TCHUNK : (LOUT - t0));

    const int idx4 = b * F4 + f4;
    const float4 tau = ((const float4*)tau_arr)[idx4];
    const float4 nrm = ((const float4*)norm_arr)[idx4];
    const float4 tk  = ((const float4*)tauK_arr)[idx4];

    const float4* __restrict__ xb = (const float4*)(x + (size_t)b * LL * FF) + f4;
    float4* __restrict__ ob = (float4*)(out + (size_t)b * LOUT * FF) + f4;

    // truncation length (correct for any tau; extra taps only add accuracy)
    const float tmax = fmaxf(fmaxf(tau.x, tau.y), fmaxf(tau.z, tau.w));
    int T = KK;
    if (tmax < 0.999f) {
        T = (int)ceilf(-32.236191f / logf(tmax));  // ln(1e-14)
        T = (T > KK) ? KK : (T < 4 ? 4 : T);
    }

    // ---- warm-up: Horner over last T taps of window at t0 ----
    float4 S = make_float4(0.f, 0.f, 0.f, 0.f);
#pragma unroll 4
    for (int i = KK - T; i < KK; ++i) {
        const float4 v = xb[(size_t)(t0 + i) * F4];
        S.x = fmaf(S.x, tau.x, v.x);
        S.y = fmaf(S.y, tau.y, v.y);
        S.z = fmaf(S.z, tau.z, v.z);
        S.w = fmaf(S.w, tau.w, v.w);
    }
    nt_store4(&ob[(size_t)t0 * F4], nrm.x * S.x, nrm.y * S.y, nrm.z * S.z,
              nrm.w * S.w);

    const bool fast =
        __all(tk.x == 0.f && tk.y == 0.f && tk.z == 0.f && tk.w == 0.f);

    if (fast) {
        if (nout == TCHUNK) {
#pragma unroll
            for (int k = 1; k < TCHUNK; ++k) {
                const int t = t0 + k;
                const float4 v = xb[(size_t)(t + KK - 1) * F4];
                S.x = fmaf(S.x, tau.x, v.x);
                S.y = fmaf(S.y, tau.y, v.y);
                S.z = fmaf(S.z, tau.z, v.z);
                S.w = fmaf(S.w, tau.w, v.w);
                nt_store4(&ob[(size_t)t * F4], nrm.x * S.x, nrm.y * S.y,
                          nrm.z * S.z, nrm.w * S.w);
            }
        } else {
            for (int k = 1; k < nout; ++k) {
                const int t = t0 + k;
                const float4 v = xb[(size_t)(t + KK - 1) * F4];
                S.x = fmaf(S.x, tau.x, v.x);
                S.y = fmaf(S.y, tau.y, v.y);
                S.z = fmaf(S.z, tau.z, v.z);
                S.w = fmaf(S.w, tau.w, v.w);
                nt_store4(&ob[(size_t)t * F4], nrm.x * S.x, nrm.y * S.y,
                          nrm.z * S.z, nrm.w * S.w);
            }
        }
    } else {
        // general sliding-window recurrence (correct for any tau)
        for (int k = 1; k < nout; ++k) {
            const int t = t0 + k;
            const float4 lead  = xb[(size_t)(t + KK - 1) * F4];
            const float4 trail = xb[(size_t)(t - 1) * F4];
            S.x = fmaf(S.x, tau.x, fmaf(-tk.x, trail.x, lead.x));
            S.y = fmaf(S.y, tau.y, fmaf(-tk.y, trail.y, lead.y));
            S.z = fmaf(S.z, tau.z, fmaf(-tk.z, trail.z, lead.z));
            S.w = fmaf(S.w, tau.w, fmaf(-tk.w, trail.w, lead.w));
            nt_store4(&ob[(size_t)t * F4], nrm.x * S.x, nrm.y * S.y,
                      nrm.z * S.z, nrm.w * S.w);
        }
    }
}

extern "C" void kernel_launch(void* const* d_in, const int* in_sizes, int n_in,
                              void* d_out, int out_size, void* d_ws, size_t ws_size,
                              hipStream_t stream) {
    const float* x    = (const float*)d_in[0];  // [B, L, F]
    const float* W    = (const float*)d_in[1];  // [F, F]
    const float* bias = (const float*)d_in[2];  // [F]
    float* out = (float*)d_out;                 // [B, LOUT, F]

    float* ws = (float*)d_ws;
    float* tau_arr  = ws;                 // [B*F]
    float* norm_arr = ws + BB * FF;       // [B*F]
    float* tauK_arr = ws + 2 * BB * FF;   // [B*F]

    tau_kernel<<<BB * 4, 128, 0, stream>>>(x, W, bias, tau_arr, norm_arr, tauK_arr);
    fir_kernel<<<BB * NPAIR, 256, 0, stream>>>(x, tau_arr, norm_arr, tauK_arr, out);
}

// Round 7
// 60.552 us; speedup vs baseline: 1.2175x; 1.2175x over previous
//
#include <hip/hip_runtime.h>
#include <math.h>

// Problem constants: B=32, L=2048, F=512, K=128, LOUT=1921
#define BB 32
#define LL 2048
#define FF 512
#define KK 128
#define LOUT (LL - KK + 1)      // 1921
#define TC 31                   // rows per chunk
#define NQ 31                   // chunk-pairs per b: thread owns chunks q and q+NQ
#define F4 (FF / 4)             // 128

// ---------------------------------------------------------------------------
// Kernel 1: tau[b,f] = sigmoid((x[b,L-1,:] . W[f,:] + bias[f]) / 10 - 3)
//           norm[b,f] = 1 / sum_{i=0..K-1} tau^i   (Horner)
//           tauK[b,f] = tau^K                       (7 squarings)
// ---------------------------------------------------------------------------
__global__ __launch_bounds__(128) void tau_kernel(const float* __restrict__ x,
                                                  const float* __restrict__ W,
                                                  const float* __restrict__ bias,
                                                  float* __restrict__ tau_out,
                                                  float* __restrict__ norm_out,
                                                  float* __restrict__ tauK_out) {
    __shared__ float feat[FF];
    const int b   = blockIdx.x >> 2;
    const int fq  = blockIdx.x & 3;
    const int tid = threadIdx.x;

    ((float4*)feat)[tid] =
        ((const float4*)(x + ((size_t)b * LL + (LL - 1)) * FF))[tid];
    __syncthreads();

    const int f = fq * 128 + tid;
    const float4* __restrict__ Wrow = (const float4*)(W + (size_t)f * FF);
    const float4* __restrict__ fv   = (const float4*)feat;

    float a0 = 0.f, a1 = 0.f, a2 = 0.f, a3 = 0.f;
#pragma unroll 4
    for (int j = 0; j < F4; j += 2) {
        float4 w0 = Wrow[j],     w1 = Wrow[j + 1];
        float4 x0 = fv[j],       x1 = fv[j + 1];
        a0 = fmaf(w0.x, x0.x, a0); a1 = fmaf(w0.y, x0.y, a1);
        a2 = fmaf(w0.z, x0.z, a2); a3 = fmaf(w0.w, x0.w, a3);
        a0 = fmaf(w1.x, x1.x, a0); a1 = fmaf(w1.y, x1.y, a1);
        a2 = fmaf(w1.z, x1.z, a2); a3 = fmaf(w1.w, x1.w, a3);
    }
    const float acc = (a0 + a1) + (a2 + a3);
    const float z   = (acc + bias[f]) * 0.1f - 3.0f;
    const float tau = 1.0f / (1.0f + expf(-z));

    float den = 1.0f;
#pragma unroll 8
    for (int i = 0; i < KK - 1; ++i) den = fmaf(den, tau, 1.0f);

    float tk = tau;
#pragma unroll
    for (int i = 0; i < 7; ++i) tk *= tk;

    const int idx = b * FF + f;
    tau_out[idx]  = tau;
    norm_out[idx] = 1.0f / den;
    tauK_out[idx] = tk;
}

// ---------------------------------------------------------------------------
// Kernel 2: dual-chain version. Grid = B*NQ blocks of 128 threads; thread
// (b, q, f4) owns TWO independent recurrences: chunks q and q+NQ (31 rows
// each). The two chains interleave in source -> 2+ independent loads in
// flight per wave regardless of compiler register minimization; tau/norm
// loads amortized; warm-up amplification drops to (T+30)/62 ~ 1.19x.
// Plain stores (r2 evidence: NT stores made x LESS L3-resident).
// ---------------------------------------------------------------------------
__global__ __launch_bounds__(128) void fir_kernel(const float* __restrict__ x,
                                                  const float* __restrict__ tau_arr,
                                                  const float* __restrict__ norm_arr,
                                                  const float* __restrict__ tauK_arr,
                                                  float* __restrict__ out) {
    const int b  = blockIdx.x / NQ;
    const int q  = blockIdx.x % NQ;
    const int f4 = threadIdx.x;

    const int t0A = q * TC;          // <= 930
    const int t0B = (q + NQ) * TC;   // <= 1891
    int noutB = LOUT - t0B;          // 31, except q=30 -> 30
    if (noutB > TC) noutB = TC;

    const int idx4 = b * F4 + f4;
    const float4 tau = ((const float4*)tau_arr)[idx4];
    const float4 nrm = ((const float4*)norm_arr)[idx4];
    const float4 tk  = ((const float4*)tauK_arr)[idx4];

    const float4* __restrict__ xb = (const float4*)(x + (size_t)b * LL * FF) + f4;
    float4* __restrict__ ob = (float4*)(out + (size_t)b * LOUT * FF) + f4;

    // truncation length (correct for any tau; extra taps only add accuracy)
    const float tmax = fmaxf(fmaxf(tau.x, tau.y), fmaxf(tau.z, tau.w));
    int T = KK;
    if (tmax < 0.999f) {
        T = (int)ceilf(-32.236191f / logf(tmax));  // ln(1e-14)
        T = (T > KK) ? KK : (T < 4 ? 4 : T);
    }

    // ---- warm-up: both chains interleaved (independent load pairs) ----
    float4 SA = make_float4(0.f, 0.f, 0.f, 0.f);
    float4 SB = make_float4(0.f, 0.f, 0.f, 0.f);
#pragma unroll 4
    for (int i = KK - T; i < KK; ++i) {
        const float4 vA = xb[(size_t)(t0A + i) * F4];
        const float4 vB = xb[(size_t)(t0B + i) * F4];
        SA.x = fmaf(SA.x, tau.x, vA.x); SB.x = fmaf(SB.x, tau.x, vB.x);
        SA.y = fmaf(SA.y, tau.y, vA.y); SB.y = fmaf(SB.y, tau.y, vB.y);
        SA.z = fmaf(SA.z, tau.z, vA.z); SB.z = fmaf(SB.z, tau.z, vB.z);
        SA.w = fmaf(SA.w, tau.w, vA.w); SB.w = fmaf(SB.w, tau.w, vB.w);
    }
    ob[(size_t)t0A * F4] =
        make_float4(nrm.x * SA.x, nrm.y * SA.y, nrm.z * SA.z, nrm.w * SA.w);
    ob[(size_t)t0B * F4] =
        make_float4(nrm.x * SB.x, nrm.y * SB.y, nrm.z * SB.z, nrm.w * SB.w);

    const bool fast =
        __all(tk.x == 0.f && tk.y == 0.f && tk.z == 0.f && tk.w == 0.f);

    if (fast) {
        // uniform dual-chain steps
#pragma unroll 4
        for (int k = 1; k < noutB; ++k) {
            const float4 vA = xb[(size_t)(t0A + k + KK - 1) * F4];
            const float4 vB = xb[(size_t)(t0B + k + KK - 1) * F4];
            SA.x = fmaf(SA.x, tau.x, vA.x); SB.x = fmaf(SB.x, tau.x, vB.x);
            SA.y = fmaf(SA.y, tau.y, vA.y); SB.y = fmaf(SB.y, tau.y, vB.y);
            SA.z = fmaf(SA.z, tau.z, vA.z); SB.z = fmaf(SB.z, tau.z, vB.z);
            SA.w = fmaf(SA.w, tau.w, vA.w); SB.w = fmaf(SB.w, tau.w, vB.w);
            ob[(size_t)(t0A + k) * F4] = make_float4(
                nrm.x * SA.x, nrm.y * SA.y, nrm.z * SA.z, nrm.w * SA.w);
            ob[(size_t)(t0B + k) * F4] = make_float4(
                nrm.x * SB.x, nrm.y * SB.y, nrm.z * SB.z, nrm.w * SB.w);
        }
        // chain-A remainder (at most 1 step, when chain B is the short tail)
        for (int k = noutB; k < TC; ++k) {
            const float4 vA = xb[(size_t)(t0A + k + KK - 1) * F4];
            SA.x = fmaf(SA.x, tau.x, vA.x);
            SA.y = fmaf(SA.y, tau.y, vA.y);
            SA.z = fmaf(SA.z, tau.z, vA.z);
            SA.w = fmaf(SA.w, tau.w, vA.w);
            ob[(size_t)(t0A + k) * F4] = make_float4(
                nrm.x * SA.x, nrm.y * SA.y, nrm.z * SA.z, nrm.w * SA.w);
        }
    } else {
        // general sliding-window recurrence (correct for any tau)
        for (int k = 1; k < noutB; ++k) {
            const float4 lA = xb[(size_t)(t0A + k + KK - 1) * F4];
            const float4 tA = xb[(size_t)(t0A + k - 1) * F4];
            const float4 lB = xb[(size_t)(t0B + k + KK - 1) * F4];
            const float4 tB = xb[(size_t)(t0B + k - 1) * F4];
            SA.x = fmaf(SA.x, tau.x, fmaf(-tk.x, tA.x, lA.x));
            SA.y = fmaf(SA.y, tau.y, fmaf(-tk.y, tA.y, lA.y));
            SA.z = fmaf(SA.z, tau.z, fmaf(-tk.z, tA.z, lA.z));
            SA.w = fmaf(SA.w, tau.w, fmaf(-tk.w, tA.w, lA.w));
            SB.x = fmaf(SB.x, tau.x, fmaf(-tk.x, tB.x, lB.x));
            SB.y = fmaf(SB.y, tau.y, fmaf(-tk.y, tB.y, lB.y));
            SB.z = fmaf(SB.z, tau.z, fmaf(-tk.z, tB.z, lB.z));
            SB.w = fmaf(SB.w, tau.w, fmaf(-tk.w, tB.w, lB.w));
            ob[(size_t)(t0A + k) * F4] = make_float4(
                nrm.x * SA.x, nrm.y * SA.y, nrm.z * SA.z, nrm.w * SA.w);
            ob[(size_t)(t0B + k) * F4] = make_float4(
                nrm.x * SB.x, nrm.y * SB.y, nrm.z * SB.z, nrm.w * SB.w);
        }
        for (int k = noutB; k < TC; ++k) {
            const float4 lA = xb[(size_t)(t0A + k + KK - 1) * F4];
            const float4 tA = xb[(size_t)(t0A + k - 1) * F4];
            SA.x = fmaf(SA.x, tau.x, fmaf(-tk.x, tA.x, lA.x));
            SA.y = fmaf(SA.y, tau.y, fmaf(-tk.y, tA.y, lA.y));
            SA.z = fmaf(SA.z, tau.z, fmaf(-tk.z, tA.z, lA.z));
            SA.w = fmaf(SA.w, tau.w, fmaf(-tk.w, tA.w, lA.w));
            ob[(size_t)(t0A + k) * F4] = make_float4(
                nrm.x * SA.x, nrm.y * SA.y, nrm.z * SA.z, nrm.w * SA.w);
        }
    }
}

extern "C" void kernel_launch(void* const* d_in, const int* in_sizes, int n_in,
                              void* d_out, int out_size, void* d_ws, size_t ws_size,
                              hipStream_t stream) {
    const float* x    = (const float*)d_in[0];  // [B, L, F]
    const float* W    = (const float*)d_in[1];  // [F, F]
    const float* bias = (const float*)d_in[2];  // [F]
    float* out = (float*)d_out;                 // [B, LOUT, F]

    float* ws = (float*)d_ws;
    float* tau_arr  = ws;                 // [B*F]
    float* norm_arr = ws + BB * FF;       // [B*F]
    float* tauK_arr = ws + 2 * BB * FF;   // [B*F]

    tau_kernel<<<BB * 4, 128, 0, stream>>>(x, W, bias, tau_arr, norm_arr, tauK_arr);
    fir_kernel<<<BB * NQ, 128, 0, stream>>>(x, tau_arr, norm_arr, tauK_arr, out);
}